// Round 6
// baseline (346.587 us; speedup 1.0000x reference)
//
#include <hip/hip_runtime.h>

#define N_NODES 50000
#define N_EDGES 1600000
#define FEAT 128
#define HIDDEN 128
#define NUM_CLASS 64

#define NBUCK 196        // ceil(50000/256) dst buckets
#define BSTRIDE 20480    // bucket region (real ~8.2K + pad ~4.8K, margin ~7K)
#define EPB 2048         // edges per bucket-pass block -> 782 blocks
#define SENTINEL (1u << 24)
#define AGG_NBN 3125     // 50000/16 dst-blocks for agg (16 dst/block, exact)
#define GEMM_TN 64
#define GEMM_BLOCKS 782  // ceil(50000/64)

typedef _Float16 h8 __attribute__((ext_vector_type(8)));

__global__ void binit_kernel(int* __restrict__ bcur, int* __restrict__ breal) {
    int b = threadIdx.x;
    if (b < NBUCK) { bcur[b] = b * BSTRIDE; breal[b] = 0; }
}

// ---- pass 1: bin edges by dst>>8 into 64B-aligned private chunks; src histogram ----
__global__ __launch_bounds__(256) void bucket_kernel(const int* __restrict__ ei,
                                                     int* __restrict__ bcur,
                                                     int* __restrict__ breal,
                                                     unsigned* __restrict__ bucket_buf,
                                                     int* __restrict__ out_cnt) {
    __shared__ int cnt[NBUCK];
    __shared__ int gbase[NBUCK];
    __shared__ int rank[NBUCK];
    const int tid = threadIdx.x;
    for (int i = tid; i < NBUCK; i += 256) { cnt[i] = 0; rank[i] = 0; }
    __syncthreads();

    const int base = blockIdx.x * EPB;
    unsigned packed[8];
    int bk[8];
#pragma unroll
    for (int j = 0; j < 8; ++j) {
        int e = base + tid + j * 256;
        if (e < N_EDGES) {
            unsigned s = (unsigned)ei[e];
            unsigned d = (unsigned)ei[N_EDGES + e];
            atomicAdd(&out_cnt[s], 1);
            bk[j] = (int)(d >> 8);
            packed[j] = s | ((d & 255u) << 16);
            atomicAdd(&cnt[bk[j]], 1);
        } else bk[j] = -1;
    }
    __syncthreads();
    // 64B-aligned private reservation per (block,bucket); pad with sentinels
    for (int i = tid; i < NBUCK; i += 256) {
        const int c = cnt[i];
        if (c > 0) {
            const int padded = (c + 15) & ~15;
            const int gb = atomicAdd(&bcur[i], padded);
            gbase[i] = gb;
            atomicAdd(&breal[i], c);
            for (int t = c; t < padded; ++t) bucket_buf[gb + t] = SENTINEL;
        }
    }
    __syncthreads();
#pragma unroll
    for (int j = 0; j < 8; ++j)
        if (bk[j] >= 0) {
            int r = atomicAdd(&rank[bk[j]], 1);
            bucket_buf[gbase[bk[j]] + r] = packed[j];
        }
}

// ---- scan REAL bucket totals -> csr_base ----
__global__ __launch_bounds__(256) void bscan_kernel(const int* __restrict__ breal,
                                                    int* __restrict__ csr_base,
                                                    int* __restrict__ row_off) {
    __shared__ int tmp[256];
    int b = threadIdx.x;
    int v = (b < NBUCK) ? breal[b] : 0;
    tmp[b] = v;
    __syncthreads();
    for (int off = 1; off < 256; off <<= 1) {
        int t = (b >= off) ? tmp[b - off] : 0;
        __syncthreads();
        tmp[b] += t;
        __syncthreads();
    }
    if (b < NBUCK) csr_base[b] = tmp[b] - v;
    if (b == 0) row_off[N_NODES] = N_EDGES;
}

// ---- pass 2: per-bucket counting sort -> csr (ushort src), row_off, in_isqrt ----
__global__ __launch_bounds__(512) void csr_kernel(const int* __restrict__ bcur,
                                                  const int* __restrict__ csr_base,
                                                  const unsigned* __restrict__ bucket_buf,
                                                  unsigned short* __restrict__ csr,
                                                  int* __restrict__ row_off,
                                                  float* __restrict__ in_isqrt) {
    __shared__ int cnt[256];
    __shared__ int cur[256];
    __shared__ int tmp[256];
    const int b = blockIdx.x;
    const int t = threadIdx.x;
    const int ebeg = b * BSTRIDE;
    const int eend = bcur[b];

    if (t < 256) cnt[t] = 0;
    __syncthreads();
    for (int e = ebeg + t; e < eend; e += 512) {
        unsigned p = bucket_buf[e];
        if (!(p >> 24)) atomicAdd(&cnt[(p >> 16) & 255u], 1);
    }
    __syncthreads();

    int v = 0;
    if (t < 256) { v = cnt[t]; tmp[t] = v; }
    __syncthreads();
    for (int off = 1; off < 256; off <<= 1) {
        int add = 0;
        if (t < 256 && t >= off) add = tmp[t - off];
        __syncthreads();
        if (t < 256) tmp[t] += add;
        __syncthreads();
    }
    if (t < 256) {
        const int my_off = csr_base[b] + tmp[t] - v;
        cur[t] = my_off;
        const int node = (b << 8) + t;
        if (node < N_NODES) {
            row_off[node] = my_off;
            in_isqrt[node] = rsqrtf((float)(v > 0 ? v : 1));
        }
    }
    __syncthreads();

    for (int e = ebeg + t; e < eend; e += 512) {
        unsigned p = bucket_buf[e];
        if (!(p >> 24)) {
            int pos = atomicAdd(&cur[(p >> 16) & 255u], 1);
            csr[pos] = (unsigned short)(p & 0xFFFFu);
        }
    }
}

// ---- dense projection: Ys[slice][n][32] (fp16) = rsqrt(out_deg[n]) * (H[n][:] @ W) ----
template <int OUT>
__global__ __launch_bounds__(256) void gemm_kernel(const float* __restrict__ H,
                                                   const float* __restrict__ Wg,
                                                   const int* __restrict__ out_cnt,
                                                   _Float16* __restrict__ Ys) {
    constexpr int NCG = OUT / 8;                      // 8-col groups: 16 / 8
    constexpr int RN = GEMM_TN * OUT / (256 * 8);     // nodes/thread: 4 / 2
    __shared__ float Hst[FEAT][GEMM_TN];              // transposed H tile, 32 KB

    const int tid = threadIdx.x;
    const int bn = blockIdx.x * GEMM_TN;

    {
        const int n = tid & 63;
        const int kg = tid >> 6;
        const int gn = bn + n;
        if (gn < N_NODES) {
            const float4* hrow = (const float4*)(H + (size_t)gn * FEAT) + kg * 8;
#pragma unroll
            for (int jj = 0; jj < 8; ++jj) {
                float4 v = hrow[jj];
                const int k0 = kg * 32 + jj * 4;
                Hst[k0 + 0][n] = v.x;
                Hst[k0 + 1][n] = v.y;
                Hst[k0 + 2][n] = v.z;
                Hst[k0 + 3][n] = v.w;
            }
        } else {
#pragma unroll
            for (int jj = 0; jj < 8; ++jj) {
                const int k0 = kg * 32 + jj * 4;
                Hst[k0 + 0][n] = 0.f; Hst[k0 + 1][n] = 0.f;
                Hst[k0 + 2][n] = 0.f; Hst[k0 + 3][n] = 0.f;
            }
        }
    }
    __syncthreads();

    const int cq = tid & (NCG - 1);
    const int ng = tid / NCG;
    const float4* W4 = (const float4*)Wg;

    float4 acc[RN][2];
#pragma unroll
    for (int i = 0; i < RN; ++i) {
        acc[i][0] = {0.f, 0.f, 0.f, 0.f};
        acc[i][1] = {0.f, 0.f, 0.f, 0.f};
    }

#pragma unroll 4
    for (int k = 0; k < FEAT; ++k) {
        const float4 w0 = W4[k * (OUT / 4) + cq * 2];
        const float4 w1 = W4[k * (OUT / 4) + cq * 2 + 1];
        if constexpr (RN == 4) {
            const float4 a = *(const float4*)&Hst[k][ng * 4];
            acc[0][0].x += a.x * w0.x; acc[0][0].y += a.x * w0.y; acc[0][0].z += a.x * w0.z; acc[0][0].w += a.x * w0.w;
            acc[0][1].x += a.x * w1.x; acc[0][1].y += a.x * w1.y; acc[0][1].z += a.x * w1.z; acc[0][1].w += a.x * w1.w;
            acc[1][0].x += a.y * w0.x; acc[1][0].y += a.y * w0.y; acc[1][0].z += a.y * w0.z; acc[1][0].w += a.y * w0.w;
            acc[1][1].x += a.y * w1.x; acc[1][1].y += a.y * w1.y; acc[1][1].z += a.y * w1.z; acc[1][1].w += a.y * w1.w;
            acc[2][0].x += a.z * w0.x; acc[2][0].y += a.z * w0.y; acc[2][0].z += a.z * w0.z; acc[2][0].w += a.z * w0.w;
            acc[2][1].x += a.z * w1.x; acc[2][1].y += a.z * w1.y; acc[2][1].z += a.z * w1.z; acc[2][1].w += a.z * w1.w;
            acc[3][0].x += a.w * w0.x; acc[3][0].y += a.w * w0.y; acc[3][0].z += a.w * w0.z; acc[3][0].w += a.w * w0.w;
            acc[3][1].x += a.w * w1.x; acc[3][1].y += a.w * w1.y; acc[3][1].z += a.w * w1.z; acc[3][1].w += a.w * w1.w;
        } else {
            const float2 a = *(const float2*)&Hst[k][ng * 2];
            acc[0][0].x += a.x * w0.x; acc[0][0].y += a.x * w0.y; acc[0][0].z += a.x * w0.z; acc[0][0].w += a.x * w0.w;
            acc[0][1].x += a.x * w1.x; acc[0][1].y += a.x * w1.y; acc[0][1].z += a.x * w1.z; acc[0][1].w += a.x * w1.w;
            acc[1][0].x += a.y * w0.x; acc[1][0].y += a.y * w0.y; acc[1][0].z += a.y * w0.z; acc[1][0].w += a.y * w0.w;
            acc[1][1].x += a.y * w1.x; acc[1][1].y += a.y * w1.y; acc[1][1].z += a.y * w1.z; acc[1][1].w += a.y * w1.w;
        }
    }

#pragma unroll
    for (int i = 0; i < RN; ++i) {
        const int gn = bn + ng * RN + i;
        if (gn < N_NODES) {
            int c = out_cnt[gn];
            const float sc = rsqrtf((float)(c < 1 ? 1 : c));
            const int sl = cq >> 2;
            const int off = (cq & 3) * 8;
            h8 r;
            r[0] = (_Float16)(acc[i][0].x * sc); r[1] = (_Float16)(acc[i][0].y * sc);
            r[2] = (_Float16)(acc[i][0].z * sc); r[3] = (_Float16)(acc[i][0].w * sc);
            r[4] = (_Float16)(acc[i][1].x * sc); r[5] = (_Float16)(acc[i][1].y * sc);
            r[6] = (_Float16)(acc[i][1].z * sc); r[7] = (_Float16)(acc[i][1].w * sc);
            *(h8*)(Ys + ((size_t)sl * N_NODES + gn) * 32 + off) = r;
        }
    }
}

// ---- sliced CSR gather-aggregate (fp16 rows) + in_isqrt + relu -> fp32 ----
template <int F>
__global__ __launch_bounds__(256) void agg_kernel(const int* __restrict__ row_off,
                                                  const unsigned short* __restrict__ csr,
                                                  const _Float16* __restrict__ Ys,
                                                  const float* __restrict__ in_isqrt,
                                                  float* __restrict__ out) {
    constexpr int NS = F / 32;               // slices: 4 (F=128) / 2 (F=64)
    const int s  = blockIdx.x & (NS - 1);
    const int nb = blockIdx.x / NS;
    const int tid = threadIdx.x;
    const int lane = tid & 63;
    const int j = lane >> 4;                 // dst sub 0..3
    const int esub = (lane >> 2) & 3;        // edge sub 0..3
    const int q = lane & 3;                  // 8-feature quarter of the 32-slice

    const int d = nb * 16 + (tid >> 6) * 4 + j;          // exact: 3125*16 = 50000
    const _Float16* Yp = Ys + (size_t)s * (N_NODES * 32) + q * 8;

    const int end = row_off[d + 1];
    float a0 = 0.f, a1 = 0.f, a2 = 0.f, a3 = 0.f, a4 = 0.f, a5 = 0.f, a6 = 0.f, a7 = 0.f;

    int e = row_off[d] + esub;
    for (; e + 4 < end; e += 8) {
        const int i0 = csr[e];
        const int i1 = csr[e + 4];
        const h8 v0 = *(const h8*)(Yp + (size_t)i0 * 32);
        const h8 v1 = *(const h8*)(Yp + (size_t)i1 * 32);
        a0 += (float)v0[0] + (float)v1[0];
        a1 += (float)v0[1] + (float)v1[1];
        a2 += (float)v0[2] + (float)v1[2];
        a3 += (float)v0[3] + (float)v1[3];
        a4 += (float)v0[4] + (float)v1[4];
        a5 += (float)v0[5] + (float)v1[5];
        a6 += (float)v0[6] + (float)v1[6];
        a7 += (float)v0[7] + (float)v1[7];
    }
    if (e < end) {
        const int i0 = csr[e];
        const h8 v0 = *(const h8*)(Yp + (size_t)i0 * 32);
        a0 += (float)v0[0]; a1 += (float)v0[1]; a2 += (float)v0[2]; a3 += (float)v0[3];
        a4 += (float)v0[4]; a5 += (float)v0[5]; a6 += (float)v0[6]; a7 += (float)v0[7];
    }

    a0 += __shfl_xor(a0, 4, 64); a0 += __shfl_xor(a0, 8, 64);
    a1 += __shfl_xor(a1, 4, 64); a1 += __shfl_xor(a1, 8, 64);
    a2 += __shfl_xor(a2, 4, 64); a2 += __shfl_xor(a2, 8, 64);
    a3 += __shfl_xor(a3, 4, 64); a3 += __shfl_xor(a3, 8, 64);
    a4 += __shfl_xor(a4, 4, 64); a4 += __shfl_xor(a4, 8, 64);
    a5 += __shfl_xor(a5, 4, 64); a5 += __shfl_xor(a5, 8, 64);
    a6 += __shfl_xor(a6, 4, 64); a6 += __shfl_xor(a6, 8, 64);
    a7 += __shfl_xor(a7, 4, 64); a7 += __shfl_xor(a7, 8, 64);

    if (esub == 0) {
        const float isq = in_isqrt[d];
        float4 r0, r1;
        r0.x = fmaxf(a0 * isq, 0.f); r0.y = fmaxf(a1 * isq, 0.f);
        r0.z = fmaxf(a2 * isq, 0.f); r0.w = fmaxf(a3 * isq, 0.f);
        r1.x = fmaxf(a4 * isq, 0.f); r1.y = fmaxf(a5 * isq, 0.f);
        r1.z = fmaxf(a6 * isq, 0.f); r1.w = fmaxf(a7 * isq, 0.f);
        float* op = out + (size_t)d * F + s * 32 + q * 8;
        *(float4*)op = r0;
        *(float4*)(op + 4) = r1;
    }
}

extern "C" void kernel_launch(void* const* d_in, const int* in_sizes, int n_in,
                              void* d_out, int out_size, void* d_ws, size_t ws_size,
                              hipStream_t stream) {
    const float* h  = (const float*)d_in[0];
    const int*   ei = (const int*)d_in[1];
    const float* W1 = (const float*)d_in[2];
    const float* W2 = (const float*)d_in[3];
    const float* W3 = (const float*)d_in[4];
    float* out = (float*)d_out;

    char* p = (char*)d_ws;
    auto alloc = [&p](size_t bytes) {
        void* r = (void*)p;
        p += (bytes + 255) & ~(size_t)255;
        return r;
    };
    int*   out_cnt  = (int*)alloc(N_NODES * sizeof(int));
    int*   row_off  = (int*)alloc((N_NODES + 1) * sizeof(int));
    int*   bcur     = (int*)alloc(NBUCK * sizeof(int));
    int*   breal    = (int*)alloc(NBUCK * sizeof(int));
    int*   csr_base = (int*)alloc(NBUCK * sizeof(int));
    unsigned short* csr = (unsigned short*)alloc((size_t)N_EDGES * sizeof(unsigned short));
    float* in_isqrt = (float*)alloc(N_NODES * sizeof(float));
    _Float16* Ys    = (_Float16*)alloc((size_t)N_NODES * HIDDEN * sizeof(_Float16));
    float* bufA     = (float*)alloc((size_t)N_NODES * HIDDEN * sizeof(float));
    float* bufB     = (float*)alloc((size_t)N_NODES * HIDDEN * sizeof(float));
    // bucket_buf (196*20480*4B = 16.1 MB) aliases bufA (25.6 MB): fully consumed
    // by csr_kernel before layer-1 agg writes bufA (stream order).
    unsigned* bucket_buf = (unsigned*)bufA;

    // ---- graph preprocessing (once; reused by all 3 layers) ----
    hipMemsetAsync(out_cnt, 0, N_NODES * sizeof(int), stream);
    binit_kernel<<<1, 256, 0, stream>>>(bcur, breal);
    bucket_kernel<<<(N_EDGES + EPB - 1) / EPB, 256, 0, stream>>>(ei, bcur, breal, bucket_buf, out_cnt);
    bscan_kernel<<<1, 256, 0, stream>>>(breal, csr_base, row_off);
    csr_kernel<<<NBUCK, 512, 0, stream>>>(bcur, csr_base, bucket_buf, csr, row_off, in_isqrt);

    // ---- layer 1 ----
    gemm_kernel<HIDDEN><<<GEMM_BLOCKS, 256, 0, stream>>>(h, W1, out_cnt, Ys);
    agg_kernel<HIDDEN><<<4 * AGG_NBN, 256, 0, stream>>>(row_off, csr, Ys, in_isqrt, bufA);

    // ---- layer 2 ----
    gemm_kernel<HIDDEN><<<GEMM_BLOCKS, 256, 0, stream>>>(bufA, W2, out_cnt, Ys);
    agg_kernel<HIDDEN><<<4 * AGG_NBN, 256, 0, stream>>>(row_off, csr, Ys, in_isqrt, bufB);

    // ---- layer 3 ----
    gemm_kernel<NUM_CLASS><<<GEMM_BLOCKS, 256, 0, stream>>>(bufB, W3, out_cnt, Ys);
    agg_kernel<NUM_CLASS><<<2 * AGG_NBN, 256, 0, stream>>>(row_off, csr, Ys, in_isqrt, out);
}

// Round 7
// 333.129 us; speedup vs baseline: 1.0404x; 1.0404x over previous
//
#include <hip/hip_runtime.h>

#define N_NODES 50000
#define N_EDGES 1600000
#define FEAT 128
#define HIDDEN 128
#define NUM_CLASS 64

#define NBUCK 196        // ceil(50000/256) dst buckets
#define BSTRIDE 16384    // bucket region (mean 8163, sigma ~90; exact packing)
#define EPB 2048         // edges per bucket-pass block -> 782 blocks
#define EPT (EPB / 256)  // edges per thread in bucket pass
#define AGG_NBN 3125     // 50000/16 dst-blocks for agg (16 dst/block, exact)
#define GEMM_TN 64
#define GEMM_BLOCKS 782  // ceil(50000/64)

typedef _Float16 h8 __attribute__((ext_vector_type(8)));

__global__ void binit_kernel(int* __restrict__ bcur) {
    int b = threadIdx.x;
    if (b < NBUCK) bcur[b] = b * BSTRIDE;
}

// ---- pass 1: per-block LDS counting sort by dst>>8, then run-contiguous copy ----
// packed word: src(16) | dst_low8(16..23) | bucket(24..31)
__global__ __launch_bounds__(256) void bucket_kernel(const int* __restrict__ ei,
                                                     int* __restrict__ bcur,
                                                     unsigned* __restrict__ bucket_buf,
                                                     int* __restrict__ out_cnt) {
    __shared__ int cnt[256];
    __shared__ int base[256];
    __shared__ int cur[256];
    __shared__ int gbase[256];
    __shared__ unsigned sorted[EPB];
    const int tid = threadIdx.x;
    cnt[tid] = 0;
    __syncthreads();

    const int ebase = blockIdx.x * EPB;
    unsigned packed[EPT];
    int bk[EPT];
#pragma unroll
    for (int j = 0; j < EPT; ++j) {
        const int e = ebase + tid + j * 256;
        if (e < N_EDGES) {
            const unsigned s = (unsigned)ei[e];
            const unsigned d = (unsigned)ei[N_EDGES + e];
            atomicAdd(&out_cnt[s], 1);
            bk[j] = (int)(d >> 8);
            packed[j] = s | ((d & 255u) << 16) | ((d >> 8) << 24);
            atomicAdd(&cnt[bk[j]], 1);
        } else bk[j] = -1;
    }
    __syncthreads();

    // exclusive scan of cnt -> base; cursor; exact global reservation
    const int v = cnt[tid];
    base[tid] = v;
    __syncthreads();
    for (int off = 1; off < 256; off <<= 1) {
        int t = (tid >= off) ? base[tid - off] : 0;
        __syncthreads();
        base[tid] += t;
        __syncthreads();
    }
    const int excl = base[tid] - v;
    __syncthreads();
    base[tid] = excl;
    cur[tid] = excl;
    if (v > 0) gbase[tid] = atomicAdd(&bcur[tid], v);
    __syncthreads();

    // scatter into LDS sorted buffer
#pragma unroll
    for (int j = 0; j < EPT; ++j)
        if (bk[j] >= 0) {
            const int pos = atomicAdd(&cur[bk[j]], 1);
            sorted[pos] = packed[j];
        }
    __syncthreads();

    // copy: consecutive sorted[i] -> consecutive global addresses within each run
    const int total = cur[255];
    for (int i = tid; i < total; i += 256) {
        const unsigned w = sorted[i];
        const int b = (int)(w >> 24);
        bucket_buf[gbase[b] + (i - base[b])] = w;
    }
}

// ---- scan bucket totals -> csr_base ----
__global__ __launch_bounds__(256) void bscan_kernel(const int* __restrict__ bcur,
                                                    int* __restrict__ csr_base,
                                                    int* __restrict__ row_off) {
    __shared__ int tmp[256];
    int b = threadIdx.x;
    int v = (b < NBUCK) ? (bcur[b] - b * BSTRIDE) : 0;
    tmp[b] = v;
    __syncthreads();
    for (int off = 1; off < 256; off <<= 1) {
        int t = (b >= off) ? tmp[b - off] : 0;
        __syncthreads();
        tmp[b] += t;
        __syncthreads();
    }
    if (b < NBUCK) csr_base[b] = tmp[b] - v;
    if (b == 0) row_off[N_NODES] = N_EDGES;
}

// ---- pass 2: per-bucket counting sort -> csr (ushort src), row_off, in_isqrt ----
__global__ __launch_bounds__(512) void csr_kernel(const int* __restrict__ bcur,
                                                  const int* __restrict__ csr_base,
                                                  const unsigned* __restrict__ bucket_buf,
                                                  unsigned short* __restrict__ csr,
                                                  int* __restrict__ row_off,
                                                  float* __restrict__ in_isqrt) {
    __shared__ int cnt[256];
    __shared__ int cur[256];
    __shared__ int tmp[256];
    const int b = blockIdx.x;
    const int t = threadIdx.x;
    const int ebeg = b * BSTRIDE;
    const int eend = bcur[b];

    if (t < 256) cnt[t] = 0;
    __syncthreads();
    for (int e = ebeg + t; e < eend; e += 512)
        atomicAdd(&cnt[(bucket_buf[e] >> 16) & 255u], 1);
    __syncthreads();

    int v = 0;
    if (t < 256) { v = cnt[t]; tmp[t] = v; }
    __syncthreads();
    for (int off = 1; off < 256; off <<= 1) {
        int add = 0;
        if (t < 256 && t >= off) add = tmp[t - off];
        __syncthreads();
        if (t < 256) tmp[t] += add;
        __syncthreads();
    }
    if (t < 256) {
        const int my_off = csr_base[b] + tmp[t] - v;
        cur[t] = my_off;
        const int node = (b << 8) + t;
        if (node < N_NODES) {
            row_off[node] = my_off;
            in_isqrt[node] = rsqrtf((float)(v > 0 ? v : 1));
        }
    }
    __syncthreads();

    for (int e = ebeg + t; e < eend; e += 512) {
        const unsigned p = bucket_buf[e];
        const int pos = atomicAdd(&cur[(p >> 16) & 255u], 1);
        csr[pos] = (unsigned short)(p & 0xFFFFu);
    }
}

// ---- dense projection: Ys[slice][n][32] (fp16) = rsqrt(out_deg[n]) * (H[n][:] @ W) ----
template <int OUT>
__global__ __launch_bounds__(256) void gemm_kernel(const float* __restrict__ H,
                                                   const float* __restrict__ Wg,
                                                   const int* __restrict__ out_cnt,
                                                   _Float16* __restrict__ Ys) {
    constexpr int NCG = OUT / 8;                      // 8-col groups: 16 / 8
    constexpr int RN = GEMM_TN * OUT / (256 * 8);     // nodes/thread: 4 / 2
    __shared__ float Hst[FEAT][GEMM_TN];              // transposed H tile, 32 KB

    const int tid = threadIdx.x;
    const int bn = blockIdx.x * GEMM_TN;

    {
        const int n = tid & 63;
        const int kg = tid >> 6;
        const int gn = bn + n;
        if (gn < N_NODES) {
            const float4* hrow = (const float4*)(H + (size_t)gn * FEAT) + kg * 8;
#pragma unroll
            for (int jj = 0; jj < 8; ++jj) {
                float4 v = hrow[jj];
                const int k0 = kg * 32 + jj * 4;
                Hst[k0 + 0][n] = v.x;
                Hst[k0 + 1][n] = v.y;
                Hst[k0 + 2][n] = v.z;
                Hst[k0 + 3][n] = v.w;
            }
        } else {
#pragma unroll
            for (int jj = 0; jj < 8; ++jj) {
                const int k0 = kg * 32 + jj * 4;
                Hst[k0 + 0][n] = 0.f; Hst[k0 + 1][n] = 0.f;
                Hst[k0 + 2][n] = 0.f; Hst[k0 + 3][n] = 0.f;
            }
        }
    }
    __syncthreads();

    const int cq = tid & (NCG - 1);
    const int ng = tid / NCG;
    const float4* W4 = (const float4*)Wg;

    float4 acc[RN][2];
#pragma unroll
    for (int i = 0; i < RN; ++i) {
        acc[i][0] = {0.f, 0.f, 0.f, 0.f};
        acc[i][1] = {0.f, 0.f, 0.f, 0.f};
    }

#pragma unroll 4
    for (int k = 0; k < FEAT; ++k) {
        const float4 w0 = W4[k * (OUT / 4) + cq * 2];
        const float4 w1 = W4[k * (OUT / 4) + cq * 2 + 1];
        if constexpr (RN == 4) {
            const float4 a = *(const float4*)&Hst[k][ng * 4];
            acc[0][0].x += a.x * w0.x; acc[0][0].y += a.x * w0.y; acc[0][0].z += a.x * w0.z; acc[0][0].w += a.x * w0.w;
            acc[0][1].x += a.x * w1.x; acc[0][1].y += a.x * w1.y; acc[0][1].z += a.x * w1.z; acc[0][1].w += a.x * w1.w;
            acc[1][0].x += a.y * w0.x; acc[1][0].y += a.y * w0.y; acc[1][0].z += a.y * w0.z; acc[1][0].w += a.y * w0.w;
            acc[1][1].x += a.y * w1.x; acc[1][1].y += a.y * w1.y; acc[1][1].z += a.y * w1.z; acc[1][1].w += a.y * w1.w;
            acc[2][0].x += a.z * w0.x; acc[2][0].y += a.z * w0.y; acc[2][0].z += a.z * w0.z; acc[2][0].w += a.z * w0.w;
            acc[2][1].x += a.z * w1.x; acc[2][1].y += a.z * w1.y; acc[2][1].z += a.z * w1.z; acc[2][1].w += a.z * w1.w;
            acc[3][0].x += a.w * w0.x; acc[3][0].y += a.w * w0.y; acc[3][0].z += a.w * w0.z; acc[3][0].w += a.w * w0.w;
            acc[3][1].x += a.w * w1.x; acc[3][1].y += a.w * w1.y; acc[3][1].z += a.w * w1.z; acc[3][1].w += a.w * w1.w;
        } else {
            const float2 a = *(const float2*)&Hst[k][ng * 2];
            acc[0][0].x += a.x * w0.x; acc[0][0].y += a.x * w0.y; acc[0][0].z += a.x * w0.z; acc[0][0].w += a.x * w0.w;
            acc[0][1].x += a.x * w1.x; acc[0][1].y += a.x * w1.y; acc[0][1].z += a.x * w1.z; acc[0][1].w += a.x * w1.w;
            acc[1][0].x += a.y * w0.x; acc[1][0].y += a.y * w0.y; acc[1][0].z += a.y * w0.z; acc[1][0].w += a.y * w0.w;
            acc[1][1].x += a.y * w1.x; acc[1][1].y += a.y * w1.y; acc[1][1].z += a.y * w1.z; acc[1][1].w += a.y * w1.w;
        }
    }

#pragma unroll
    for (int i = 0; i < RN; ++i) {
        const int gn = bn + ng * RN + i;
        if (gn < N_NODES) {
            int c = out_cnt[gn];
            const float sc = rsqrtf((float)(c < 1 ? 1 : c));
            const int sl = cq >> 2;
            const int off = (cq & 3) * 8;
            h8 r;
            r[0] = (_Float16)(acc[i][0].x * sc); r[1] = (_Float16)(acc[i][0].y * sc);
            r[2] = (_Float16)(acc[i][0].z * sc); r[3] = (_Float16)(acc[i][0].w * sc);
            r[4] = (_Float16)(acc[i][1].x * sc); r[5] = (_Float16)(acc[i][1].y * sc);
            r[6] = (_Float16)(acc[i][1].z * sc); r[7] = (_Float16)(acc[i][1].w * sc);
            *(h8*)(Ys + ((size_t)sl * N_NODES + gn) * 32 + off) = r;
        }
    }
}

// ---- sliced CSR gather-aggregate (fp16 rows) + in_isqrt + relu -> fp32 ----
template <int F>
__global__ __launch_bounds__(256) void agg_kernel(const int* __restrict__ row_off,
                                                  const unsigned short* __restrict__ csr,
                                                  const _Float16* __restrict__ Ys,
                                                  const float* __restrict__ in_isqrt,
                                                  float* __restrict__ out) {
    constexpr int NS = F / 32;               // slices: 4 (F=128) / 2 (F=64)
    const int s  = blockIdx.x & (NS - 1);
    const int nb = blockIdx.x / NS;
    const int tid = threadIdx.x;
    const int lane = tid & 63;
    const int j = lane >> 4;                 // dst sub 0..3
    const int esub = (lane >> 2) & 3;        // edge sub 0..3
    const int q = lane & 3;                  // 8-feature quarter of the 32-slice

    const int d = nb * 16 + (tid >> 6) * 4 + j;          // exact: 3125*16 = 50000
    const _Float16* Yp = Ys + (size_t)s * (N_NODES * 32) + q * 8;

    const int end = row_off[d + 1];
    float a0 = 0.f, a1 = 0.f, a2 = 0.f, a3 = 0.f, a4 = 0.f, a5 = 0.f, a6 = 0.f, a7 = 0.f;

    int e = row_off[d] + esub;
    for (; e + 4 < end; e += 8) {
        const int i0 = csr[e];
        const int i1 = csr[e + 4];
        const h8 v0 = *(const h8*)(Yp + (size_t)i0 * 32);
        const h8 v1 = *(const h8*)(Yp + (size_t)i1 * 32);
        a0 += (float)v0[0] + (float)v1[0];
        a1 += (float)v0[1] + (float)v1[1];
        a2 += (float)v0[2] + (float)v1[2];
        a3 += (float)v0[3] + (float)v1[3];
        a4 += (float)v0[4] + (float)v1[4];
        a5 += (float)v0[5] + (float)v1[5];
        a6 += (float)v0[6] + (float)v1[6];
        a7 += (float)v0[7] + (float)v1[7];
    }
    if (e < end) {
        const int i0 = csr[e];
        const h8 v0 = *(const h8*)(Yp + (size_t)i0 * 32);
        a0 += (float)v0[0]; a1 += (float)v0[1]; a2 += (float)v0[2]; a3 += (float)v0[3];
        a4 += (float)v0[4]; a5 += (float)v0[5]; a6 += (float)v0[6]; a7 += (float)v0[7];
    }

    a0 += __shfl_xor(a0, 4, 64); a0 += __shfl_xor(a0, 8, 64);
    a1 += __shfl_xor(a1, 4, 64); a1 += __shfl_xor(a1, 8, 64);
    a2 += __shfl_xor(a2, 4, 64); a2 += __shfl_xor(a2, 8, 64);
    a3 += __shfl_xor(a3, 4, 64); a3 += __shfl_xor(a3, 8, 64);
    a4 += __shfl_xor(a4, 4, 64); a4 += __shfl_xor(a4, 8, 64);
    a5 += __shfl_xor(a5, 4, 64); a5 += __shfl_xor(a5, 8, 64);
    a6 += __shfl_xor(a6, 4, 64); a6 += __shfl_xor(a6, 8, 64);
    a7 += __shfl_xor(a7, 4, 64); a7 += __shfl_xor(a7, 8, 64);

    if (esub == 0) {
        const float isq = in_isqrt[d];
        float4 r0, r1;
        r0.x = fmaxf(a0 * isq, 0.f); r0.y = fmaxf(a1 * isq, 0.f);
        r0.z = fmaxf(a2 * isq, 0.f); r0.w = fmaxf(a3 * isq, 0.f);
        r1.x = fmaxf(a4 * isq, 0.f); r1.y = fmaxf(a5 * isq, 0.f);
        r1.z = fmaxf(a6 * isq, 0.f); r1.w = fmaxf(a7 * isq, 0.f);
        float* op = out + (size_t)d * F + s * 32 + q * 8;
        *(float4*)op = r0;
        *(float4*)(op + 4) = r1;
    }
}

extern "C" void kernel_launch(void* const* d_in, const int* in_sizes, int n_in,
                              void* d_out, int out_size, void* d_ws, size_t ws_size,
                              hipStream_t stream) {
    const float* h  = (const float*)d_in[0];
    const int*   ei = (const int*)d_in[1];
    const float* W1 = (const float*)d_in[2];
    const float* W2 = (const float*)d_in[3];
    const float* W3 = (const float*)d_in[4];
    float* out = (float*)d_out;

    char* p = (char*)d_ws;
    auto alloc = [&p](size_t bytes) {
        void* r = (void*)p;
        p += (bytes + 255) & ~(size_t)255;
        return r;
    };
    int*   out_cnt  = (int*)alloc(N_NODES * sizeof(int));
    int*   row_off  = (int*)alloc((N_NODES + 1) * sizeof(int));
    int*   bcur     = (int*)alloc(NBUCK * sizeof(int));
    int*   csr_base = (int*)alloc(NBUCK * sizeof(int));
    unsigned short* csr = (unsigned short*)alloc((size_t)N_EDGES * sizeof(unsigned short));
    float* in_isqrt = (float*)alloc(N_NODES * sizeof(float));
    _Float16* Ys    = (_Float16*)alloc((size_t)N_NODES * HIDDEN * sizeof(_Float16));
    float* bufA     = (float*)alloc((size_t)N_NODES * HIDDEN * sizeof(float));
    float* bufB     = (float*)alloc((size_t)N_NODES * HIDDEN * sizeof(float));
    // bucket_buf (196*16384*4B = 12.85 MB) aliases bufA (25.6 MB): fully consumed
    // by csr_kernel before layer-1 agg writes bufA (stream order).
    unsigned* bucket_buf = (unsigned*)bufA;

    // ---- graph preprocessing (once; reused by all 3 layers) ----
    hipMemsetAsync(out_cnt, 0, N_NODES * sizeof(int), stream);
    binit_kernel<<<1, 256, 0, stream>>>(bcur);
    bucket_kernel<<<(N_EDGES + EPB - 1) / EPB, 256, 0, stream>>>(ei, bcur, bucket_buf, out_cnt);
    bscan_kernel<<<1, 256, 0, stream>>>(bcur, csr_base, row_off);
    csr_kernel<<<NBUCK, 512, 0, stream>>>(bcur, csr_base, bucket_buf, csr, row_off, in_isqrt);

    // ---- layer 1 ----
    gemm_kernel<HIDDEN><<<GEMM_BLOCKS, 256, 0, stream>>>(h, W1, out_cnt, Ys);
    agg_kernel<HIDDEN><<<4 * AGG_NBN, 256, 0, stream>>>(row_off, csr, Ys, in_isqrt, bufA);

    // ---- layer 2 ----
    gemm_kernel<HIDDEN><<<GEMM_BLOCKS, 256, 0, stream>>>(bufA, W2, out_cnt, Ys);
    agg_kernel<HIDDEN><<<4 * AGG_NBN, 256, 0, stream>>>(row_off, csr, Ys, in_isqrt, bufB);

    // ---- layer 3 ----
    gemm_kernel<NUM_CLASS><<<GEMM_BLOCKS, 256, 0, stream>>>(bufB, W3, out_cnt, Ys);
    agg_kernel<NUM_CLASS><<<2 * AGG_NBN, 256, 0, stream>>>(row_off, csr, Ys, in_isqrt, out);
}